// Round 1
// baseline (1089.420 us; speedup 1.0000x reference)
//
#include <hip/hip_runtime.h>
#include <cstdint>
#include <cstddef>

#define N_TOK  8192
#define HDIM   2048
#define NEXP   8
#define KCAP   1024
#define DFF    5461
#define DFF_PB 5504   // padded N for WgT/WuT (rows of transposed weights)
#define DFF_PA 5472   // padded K for act / gemm2 (multiple of 32)

typedef unsigned short u16;
typedef short bf16x8 __attribute__((ext_vector_type(8)));
typedef float f32x4  __attribute__((ext_vector_type(4)));

__device__ __forceinline__ u16 f2bf(float f) {
  uint32_t u = __float_as_uint(f);
  uint32_t r = (u + 0x7FFFu + ((u >> 16) & 1u)) >> 16;
  return (u16)r;
}

__device__ __forceinline__ uint32_t rotl32(uint32_t v, int d) {
  return (v << d) | (v >> (32 - d));
}

// JAX threefry2x32, key = (0, 42), partitionable scheme: counter=(0,i), bits = x0^x1.
__device__ uint32_t threefry_bits(uint32_t idx) {
  const uint32_t ks0 = 0u, ks1 = 42u, ks2 = 0u ^ 42u ^ 0x1BD11BDAu;
  uint32_t x0 = 0u + ks0;
  uint32_t x1 = idx + ks1;
#define TFR(d) { x0 += x1; x1 = rotl32(x1, d); x1 ^= x0; }
  TFR(13) TFR(15) TFR(26) TFR(6)
  x0 += ks1; x1 += ks2 + 1u;
  TFR(17) TFR(29) TFR(16) TFR(24)
  x0 += ks2; x1 += ks0 + 2u;
  TFR(13) TFR(15) TFR(26) TFR(6)
  x0 += ks0; x1 += ks1 + 3u;
  TFR(17) TFR(29) TFR(16) TFR(24)
  x0 += ks1; x1 += ks2 + 4u;
  TFR(13) TFR(15) TFR(26) TFR(6)
  x0 += ks2; x1 += ks0 + 5u;
#undef TFR
  return x0 ^ x1;
}

// ---------------- router: clean_h + gumbel -> softmax, stored transposed [E][n_tok]
__global__ __launch_bounds__(256) void router_kernel(const float* __restrict__ x,
    const float* __restrict__ rw, const float* __restrict__ rb,
    float* __restrict__ SmT)
{
  const int lane = threadIdx.x & 63;
  const int wid  = threadIdx.x >> 6;
  const int t = blockIdx.x * 4 + wid;     // one token per wave
  const float* xr = x + (size_t)t * HDIM;
  float acc[8] = {0.f,0.f,0.f,0.f,0.f,0.f,0.f,0.f};
#pragma unroll
  for (int it = 0; it < HDIM / 64; ++it) {
    int h = lane + it * 64;
    float xv = xr[h];
    const float4* wp = (const float4*)(rw + h * 8);
    float4 w0 = wp[0], w1 = wp[1];
    acc[0] = fmaf(xv, w0.x, acc[0]);
    acc[1] = fmaf(xv, w0.y, acc[1]);
    acc[2] = fmaf(xv, w0.z, acc[2]);
    acc[3] = fmaf(xv, w0.w, acc[3]);
    acc[4] = fmaf(xv, w1.x, acc[4]);
    acc[5] = fmaf(xv, w1.y, acc[5]);
    acc[6] = fmaf(xv, w1.z, acc[6]);
    acc[7] = fmaf(xv, w1.w, acc[7]);
  }
#pragma unroll
  for (int m = 32; m >= 1; m >>= 1) {
#pragma unroll
    for (int e = 0; e < 8; ++e) acc[e] += __shfl_xor(acc[e], m, 64);
  }
  if (lane == 0) {
    float h[8];
#pragma unroll
    for (int e = 0; e < 8; ++e) {
      uint32_t bits = threefry_bits((uint32_t)(t * 8 + e));
      float u = __uint_as_float((bits >> 9) | 0x3f800000u) - 1.0f;
      u = fmaxf(u, 0.0f);
      float g = -logf(-logf(u + 1e-10f) + 1e-10f);
      h[e] = acc[e] + rb[e] + g;
    }
    float mx = h[0];
#pragma unroll
    for (int e = 1; e < 8; ++e) mx = fmaxf(mx, h[e]);
    float ex[8]; float s = 0.f;
#pragma unroll
    for (int e = 0; e < 8; ++e) { ex[e] = expf(h[e] - mx); s += ex[e]; }
#pragma unroll
    for (int e = 0; e < 8; ++e) SmT[e * N_TOK + t] = ex[e] / s;
  }
}

// ---------------- exact top-1024-of-8192 per expert via 4-pass radix select
__global__ __launch_bounds__(1024) void select_topk(const float* __restrict__ SmT,
    uint32_t* __restrict__ selTok, float* __restrict__ selW)
{
  const int e = blockIdx.x;
  const int tid = threadIdx.x;
  const float* v = SmT + (size_t)e * N_TOK;
  __shared__ uint32_t hist[256];
  __shared__ uint32_t sh_byte, sh_kk, sh_cnt, sh_eqc;
  uint32_t bitsv[8];
#pragma unroll
  for (int i = 0; i < 8; ++i) bitsv[i] = __float_as_uint(v[tid + i * 1024]);
  uint32_t prefix = 0;
  uint32_t kk = KCAP;
  for (int s = 3; s >= 0; --s) {
    if (tid < 256) hist[tid] = 0;
    __syncthreads();
    uint32_t himask = (s == 3) ? 0u : (0xFFFFFFFFu << ((s + 1) * 8));
#pragma unroll
    for (int i = 0; i < 8; ++i) {
      uint32_t b = bitsv[i];
      if ((b & himask) == prefix) atomicAdd(&hist[(b >> (s * 8)) & 255u], 1u);
    }
    __syncthreads();
    if (tid == 0) {
      uint32_t cum = 0; uint32_t bsel = 0, kn = kk;
      for (int b = 255; b >= 0; --b) {
        uint32_t c = hist[b];
        if (cum + c >= kk) { bsel = (uint32_t)b; kn = kk - cum; break; }
        cum += c;
      }
      sh_byte = bsel; sh_kk = kn;
    }
    __syncthreads();
    prefix |= sh_byte << (s * 8);
    kk = sh_kk;
  }
  const uint32_t T = prefix;
  const uint32_t need = kk;
  if (tid == 0) { sh_cnt = 0; sh_eqc = 0; }
  __syncthreads();
#pragma unroll
  for (int i = 0; i < 8; ++i) {
    uint32_t b = bitsv[i];
    if (b > T) {
      uint32_t p = atomicAdd(&sh_cnt, 1u);
      selTok[e * KCAP + p] = (uint32_t)(tid + i * 1024);
      selW[e * KCAP + p] = __uint_as_float(b);
    } else if (b == T) {
      atomicAdd(&sh_eqc, 1u);
    }
  }
  __syncthreads();
  if (sh_eqc == need) {
#pragma unroll
    for (int i = 0; i < 8; ++i) {
      if (bitsv[i] == T) {
        uint32_t p = atomicAdd(&sh_cnt, 1u);
        selTok[e * KCAP + p] = (uint32_t)(tid + i * 1024);
        selW[e * KCAP + p] = __uint_as_float(T);
      }
    }
  } else if (tid == 0) {
    uint32_t p = sh_cnt, rem = need;
    for (int t = 0; t < N_TOK && rem > 0u; ++t) {
      if (__float_as_uint(v[t]) == T) {
        selTok[e * KCAP + p] = (uint32_t)t;
        selW[e * KCAP + p] = __uint_as_float(T);
        ++p; --rem;
      }
    }
  }
}

// ---------------- gather selected token rows, fp32 -> bf16
__global__ __launch_bounds__(256) void gather_kernel(const float* __restrict__ x,
    const uint32_t* __restrict__ selTok, u16* __restrict__ Xsel)
{
  const int slot = blockIdx.x;
  const int tid = threadIdx.x;
  const uint32_t tok = selTok[slot];
  const float4* src = (const float4*)(x + (size_t)tok * HDIM);
  float4 a = src[tid * 2], b = src[tid * 2 + 1];
  union { u16 h[8]; uint4 vv; } pk;
  pk.h[0] = f2bf(a.x); pk.h[1] = f2bf(a.y); pk.h[2] = f2bf(a.z); pk.h[3] = f2bf(a.w);
  pk.h[4] = f2bf(b.x); pk.h[5] = f2bf(b.y); pk.h[6] = f2bf(b.z); pk.h[7] = f2bf(b.w);
  ((uint4*)(Xsel + (size_t)slot * HDIM))[tid] = pk.vv;
}

// ---------------- transpose + fp32->bf16: out[j][i] = in[i][j], zero-padded
__global__ __launch_bounds__(256) void transpose_convert(const float* __restrict__ in,
    int rows_in, int cols_in, u16* __restrict__ out, int out_cols)
{
  __shared__ float tile[32][33];
  const int bi = blockIdx.y;
  const int bj = blockIdx.x;
  const int tx = threadIdx.x, ty = threadIdx.y;
#pragma unroll
  for (int t = 0; t < 4; ++t) {
    int r = bi * 32 + ty + t * 8, c = bj * 32 + tx;
    float vv = (r < rows_in && c < cols_in) ? in[(size_t)r * cols_in + c] : 0.0f;
    tile[ty + t * 8][tx] = vv;
  }
  __syncthreads();
#pragma unroll
  for (int t = 0; t < 4; ++t) {
    int oj = bj * 32 + ty + t * 8;
    int oi = bi * 32 + tx;
    out[(size_t)oj * out_cols + oi] = f2bf(tile[tx][ty + t * 8]);
  }
}

// ---------------- async global->LDS staging helper
#if defined(__has_builtin)
#  if __has_builtin(__builtin_amdgcn_global_load_lds)
#    define HAVE_GLD 1
#  endif
#endif
#ifdef HAVE_GLD
#define GLD16(gp, lp) __builtin_amdgcn_global_load_lds( \
    (const __attribute__((address_space(1))) void*)(gp), \
    (__attribute__((address_space(3))) void*)(lp), 16, 0, 0)
#define STG(gp, lp) GLD16(gp, lp)
#define WAIT_STAGE8() asm volatile("s_waitcnt vmcnt(8)" ::: "memory")
#define WAIT_STAGE4() asm volatile("s_waitcnt vmcnt(4)" ::: "memory")
#define WAIT_STAGE0() asm volatile("s_waitcnt vmcnt(0)" ::: "memory")
#else
#define STG(gp, lp) (*(bf16x8*)(lp) = *(const bf16x8*)(gp))
#define WAIT_STAGE8() asm volatile("s_waitcnt vmcnt(0) lgkmcnt(0)" ::: "memory")
#define WAIT_STAGE4() asm volatile("s_waitcnt vmcnt(0) lgkmcnt(0)" ::: "memory")
#define WAIT_STAGE0() asm volatile("s_waitcnt vmcnt(0) lgkmcnt(0)" ::: "memory")
#endif
// Raw barrier: does NOT drain vmcnt (unlike __syncthreads), "memory" clobber
// keeps LDS loads/stores and staging issues ordered across it at IR level.
#define BARRIER() asm volatile("s_barrier" ::: "memory")

// ======================================================================
// GEMM1: act = silu(Xsel*WgT + bg) .* (Xsel*WuT + bu), bf16 out
// Ring-4 LDS pipeline (T3+T4): BK=32, lookahead 3 K-tiles, vmcnt(8) counted
// waits (never 0 in steady state). 8 waves (2M x 4N), block tile 256M x 128N
// (x2 for gate+up). Conflict-free swizzle: chunk p of row r holds global
// k-chunk p ^ ((r>>1)&3)  -> every 8-lane group of a ds_read_b128 hits 8
// distinct 16B slots (2-way max per 64-lane wave = free per m136).
// Race safety: stage of tile t+3 targets slot (t-1)&3 whose last reads
// completed before the barrier preceding the issue (each wave drains its
// lgkmcnt before its own MFMA, hence before arriving at the phase barrier);
// vmcnt(8)+barrier at each tile boundary proves tile t+1 fully landed.
// ======================================================================
__global__ __launch_bounds__(512, 2) void gemm1_kernel(
    const u16* __restrict__ Xsel,  // [8192][2048] bf16
    const u16* __restrict__ WgT,   // [5504][2048] bf16 (N-major, K-contig)
    const u16* __restrict__ WuT,   // [5504][2048]
    const float* __restrict__ bg, const float* __restrict__ bu,
    u16* __restrict__ act)         // [8192][5472] bf16
{
  __shared__ u16 As [4][256 * 32];   // 64 KB
  __shared__ u16 Bgs[4][128 * 32];   // 32 KB
  __shared__ u16 Bus[4][128 * 32];   // 32 KB  (total 128 KB -> 1 block/CU)

  const int id = blockIdx.x;                   // 1376 = 8 * 172
  const int wg = (id & 7) * 172 + (id >> 3);   // XCD-chunked bijection
  const int bm = wg & 31;                      // 0..31  (M tiles of 256)
  const int bn = wg >> 5;                      // 0..42  (N tiles of 128)

  const int tid = threadIdx.x;
  // staging: A = 1024 16B-chunks (2/thread), Bg/Bu = 512 each (1/thread)
  const int c0 = tid, c1 = tid + 512;
  const int r0 = c0 >> 2, p0 = ((c0 & 3) ^ ((r0 >> 1) & 3)) * 8;
  const int r1 = c1 >> 2, p1 = ((c1 & 3) ^ ((r1 >> 1) & 3)) * 8;
  const int rb = tid >> 2, pb = ((tid & 3) ^ ((rb >> 1) & 3)) * 8;
  const u16* ag0 = Xsel + (size_t)(bm * 256 + r0) * HDIM + p0;
  const u16* ag1 = Xsel + (size_t)(bm * 256 + r1) * HDIM + p1;
  const u16* gg  = WgT  + (size_t)(bn * 128 + rb) * HDIM + pb;
  const u16* ug  = WuT  + (size_t)(bn * 128 + rb) * HDIM + pb;

#define G1_STAGE_A(tt) { u16* s_ = As[(tt) & 3]; \
    STG(ag0 + (tt) * 32, s_ + c0 * 8); \
    STG(ag1 + (tt) * 32, s_ + c1 * 8); }
#define G1_STAGE_B(tt) { \
    STG(gg + (tt) * 32, Bgs[(tt) & 3] + tid * 8); \
    STG(ug + (tt) * 32, Bus[(tt) & 3] + tid * 8); }

  f32x4 accg[8][2], accu[8][2];
  const f32x4 z4 = {0.f, 0.f, 0.f, 0.f};
#pragma unroll
  for (int i = 0; i < 8; ++i)
#pragma unroll
    for (int j = 0; j < 2; ++j) { accg[i][j] = z4; accu[i][j] = z4; }

  const int lane = tid & 63, wid = tid >> 6;
  const int wm = wid >> 2, wn = wid & 3;       // wave tile 128M x 32N
  const int fr = lane & 15, ck = lane >> 4;
  const int sw8 = (ck ^ ((fr >> 1) & 3)) * 8;
  const int aoff = (wm * 128 + fr) * 32 + sw8;
  const int boff = (wn * 32 + fr) * 32 + sw8;

  // prologue: tiles 0,1,2 in flight; wait tile 0 (leave 8 = tiles 1,2)
  G1_STAGE_A(0) G1_STAGE_B(0)
  G1_STAGE_A(1) G1_STAGE_B(1)
  G1_STAGE_A(2) G1_STAGE_B(2)
  WAIT_STAGE8(); BARRIER();

  for (int t = 0; t < 64; ++t) {
    const u16* Ab = As[t & 3];
    const u16* Gb = Bgs[t & 3];
    const u16* Ub = Bus[t & 3];
    // ---- phase 0: A frags 0-3 + all B frags; stage A(t+3)
    bf16x8 a0[4], gf[2], uf[2];
#pragma unroll
    for (int i = 0; i < 4; ++i) a0[i] = *(const bf16x8*)&Ab[aoff + i * (16 * 32)];
#pragma unroll
    for (int j = 0; j < 2; ++j) {
      gf[j] = *(const bf16x8*)&Gb[boff + j * (16 * 32)];
      uf[j] = *(const bf16x8*)&Ub[boff + j * (16 * 32)];
    }
    if (t + 3 < 64) G1_STAGE_A(t + 3)
    BARRIER();
    __builtin_amdgcn_s_setprio(1);
#pragma unroll
    for (int i = 0; i < 4; ++i)
#pragma unroll
      for (int j = 0; j < 2; ++j) {
        accg[i][j] = __builtin_amdgcn_mfma_f32_16x16x32_bf16(a0[i], gf[j], accg[i][j], 0, 0, 0);
        accu[i][j] = __builtin_amdgcn_mfma_f32_16x16x32_bf16(a0[i], uf[j], accu[i][j], 0, 0, 0);
      }
    __builtin_amdgcn_s_setprio(0);
    BARRIER();
    // ---- phase 1: A frags 4-7 (B reused from regs); stage B(t+3)
    bf16x8 a1[4];
#pragma unroll
    for (int i = 0; i < 4; ++i) a1[i] = *(const bf16x8*)&Ab[aoff + (64 + i * 16) * 32];
    if (t + 3 < 64) G1_STAGE_B(t + 3)
    BARRIER();
    __builtin_amdgcn_s_setprio(1);
#pragma unroll
    for (int i = 0; i < 4; ++i)
#pragma unroll
      for (int j = 0; j < 2; ++j) {
        accg[4 + i][j] = __builtin_amdgcn_mfma_f32_16x16x32_bf16(a1[i], gf[j], accg[4 + i][j], 0, 0, 0);
        accu[4 + i][j] = __builtin_amdgcn_mfma_f32_16x16x32_bf16(a1[i], uf[j], accu[4 + i][j], 0, 0, 0);
      }
    __builtin_amdgcn_s_setprio(0);
    // tile boundary: ensure tile t+1 landed (8 = tiles t+2,t+3 stay in flight)
    if (t < 61)      { WAIT_STAGE8(); }
    else if (t == 61){ WAIT_STAGE4(); }
    else             { WAIT_STAGE0(); }
    BARRIER();
  }

  // epilogue: silu(g+bg)*(u+bu) -> bf16; writes pad cols [DFF,DFF_PA) as 0
  const int rv = ck * 4;
#pragma unroll
  for (int i8 = 0; i8 < 8; ++i8) {
#pragma unroll
    for (int v = 0; v < 4; ++v) {
      const int row = bm * 256 + wm * 128 + i8 * 16 + rv + v;
      u16* arow = act + (size_t)row * DFF_PA;
#pragma unroll
      for (int j = 0; j < 2; ++j) {
        const int col = bn * 128 + wn * 32 + j * 16 + fr;
        if (col < DFF_PA) {
          u16 ov = 0;
          if (col < DFF) {
            float gv = accg[i8][j][v] + bg[col];
            float uv = accu[i8][j][v] + bu[col];
            ov = f2bf((gv / (1.0f + expf(-gv))) * uv);
          }
          arow[col] = ov;
        }
      }
    }
  }
#undef G1_STAGE_A
#undef G1_STAGE_B
}

// ======================================================================
// GEMM2: y[tok] += G * (act*WdT + bd)  (fp32 atomics)
// Same ring-4 pipeline; block tile 256M x 256N, 8 waves (2M x 4N).
// ======================================================================
__global__ __launch_bounds__(512, 2) void gemm2_kernel(
    const u16* __restrict__ act,   // [8192][5472] bf16
    const u16* __restrict__ WdT,   // [2048][5472] bf16
    const float* __restrict__ bd,  // [2048]
    const uint32_t* __restrict__ selTok,
    const float* __restrict__ selW,
    float* __restrict__ y)         // [8192][2048] fp32
{
  __shared__ u16 As[4][256 * 32];  // 64 KB
  __shared__ u16 Bs[4][256 * 32];  // 64 KB

  const int id = blockIdx.x;                  // 256 = 8 * 32
  const int wg = (id & 7) * 32 + (id >> 3);   // XCD-chunked bijection
  const int bm = wg & 31;                     // 0..31
  const int bn = wg >> 5;                     // 0..7

  const int tid = threadIdx.x;
  const int c0 = tid, c1 = tid + 512;
  const int r0 = c0 >> 2, p0 = ((c0 & 3) ^ ((r0 >> 1) & 3)) * 8;
  const int r1 = c1 >> 2, p1 = ((c1 & 3) ^ ((r1 >> 1) & 3)) * 8;
  const u16* ag0 = act + (size_t)(bm * 256 + r0) * DFF_PA + p0;
  const u16* ag1 = act + (size_t)(bm * 256 + r1) * DFF_PA + p1;
  const u16* bg0 = WdT + (size_t)(bn * 256 + r0) * DFF_PA + p0;
  const u16* bg1 = WdT + (size_t)(bn * 256 + r1) * DFF_PA + p1;

#define G2_STAGE_A(tt) { u16* s_ = As[(tt) & 3]; \
    STG(ag0 + (tt) * 32, s_ + c0 * 8); \
    STG(ag1 + (tt) * 32, s_ + c1 * 8); }
#define G2_STAGE_B(tt) { u16* s_ = Bs[(tt) & 3]; \
    STG(bg0 + (tt) * 32, s_ + c0 * 8); \
    STG(bg1 + (tt) * 32, s_ + c1 * 8); }

  f32x4 acc[8][4];
  const f32x4 z4 = {0.f, 0.f, 0.f, 0.f};
#pragma unroll
  for (int i = 0; i < 8; ++i)
#pragma unroll
    for (int j = 0; j < 4; ++j) acc[i][j] = z4;

  const int lane = tid & 63, wid = tid >> 6;
  const int wm = wid >> 2, wn = wid & 3;      // wave tile 128M x 64N
  const int fr = lane & 15, ck = lane >> 4;
  const int sw8 = (ck ^ ((fr >> 1) & 3)) * 8;
  const int aoff = (wm * 128 + fr) * 32 + sw8;
  const int boff = (wn * 64 + fr) * 32 + sw8;

  G2_STAGE_A(0) G2_STAGE_B(0)
  G2_STAGE_A(1) G2_STAGE_B(1)
  G2_STAGE_A(2) G2_STAGE_B(2)
  WAIT_STAGE8(); BARRIER();

  const int NT = DFF_PA / 32;   // 171
  for (int t = 0; t < NT; ++t) {
    const u16* Ab = As[t & 3];
    const u16* Bb = Bs[t & 3];
    bf16x8 a0[4], bf[4];
#pragma unroll
    for (int i = 0; i < 4; ++i) a0[i] = *(const bf16x8*)&Ab[aoff + i * (16 * 32)];
#pragma unroll
    for (int j = 0; j < 4; ++j) bf[j] = *(const bf16x8*)&Bb[boff + j * (16 * 32)];
    if (t + 3 < NT) G2_STAGE_A(t + 3)
    BARRIER();
    __builtin_amdgcn_s_setprio(1);
#pragma unroll
    for (int i = 0; i < 4; ++i)
#pragma unroll
      for (int j = 0; j < 4; ++j)
        acc[i][j] = __builtin_amdgcn_mfma_f32_16x16x32_bf16(a0[i], bf[j], acc[i][j], 0, 0, 0);
    __builtin_amdgcn_s_setprio(0);
    BARRIER();
    bf16x8 a1[4];
#pragma unroll
    for (int i = 0; i < 4; ++i) a1[i] = *(const bf16x8*)&Ab[aoff + (64 + i * 16) * 32];
    if (t + 3 < NT) G2_STAGE_B(t + 3)
    BARRIER();
    __builtin_amdgcn_s_setprio(1);
#pragma unroll
    for (int i = 0; i < 4; ++i)
#pragma unroll
      for (int j = 0; j < 4; ++j)
        acc[4 + i][j] = __builtin_amdgcn_mfma_f32_16x16x32_bf16(a1[i], bf[j], acc[4 + i][j], 0, 0, 0);
    __builtin_amdgcn_s_setprio(0);
    if (t < NT - 3)       { WAIT_STAGE8(); }
    else if (t == NT - 3) { WAIT_STAGE4(); }
    else                  { WAIT_STAGE0(); }
    BARRIER();
  }

  const int rv = ck * 4;
#pragma unroll
  for (int i8 = 0; i8 < 8; ++i8) {
#pragma unroll
    for (int v = 0; v < 4; ++v) {
      const int srow = bm * 256 + wm * 128 + i8 * 16 + rv + v;   // slot
      const uint32_t tok = selTok[srow];
      const float w = selW[srow];
      float* yrow = y + (size_t)tok * HDIM;
#pragma unroll
      for (int j = 0; j < 4; ++j) {
        const int col = bn * 256 + wn * 64 + j * 16 + fr;
        atomicAdd(&yrow[col], w * (acc[i8][j][v] + bd[col]));
      }
    }
  }
#undef G2_STAGE_A
#undef G2_STAGE_B
}

extern "C" void kernel_launch(void* const* d_in, const int* in_sizes, int n_in,
                              void* d_out, int out_size, void* d_ws, size_t ws_size,
                              hipStream_t stream) {
  const float* x      = (const float*)d_in[0];
  const float* rw     = (const float*)d_in[1];
  const float* rb     = (const float*)d_in[2];
  const float* w_gate = (const float*)d_in[3];
  const float* b_gate = (const float*)d_in[4];
  const float* w_up   = (const float*)d_in[5];
  const float* b_up   = (const float*)d_in[6];
  const float* w_down = (const float*)d_in[7];
  const float* b_down = (const float*)d_in[8];
  float* y = (float*)d_out;

  uint8_t* ws = (uint8_t*)d_ws;
  float*    SmT    = (float*)(ws + 0);              //   262144 B
  uint32_t* selTok = (uint32_t*)(ws + 262144);      //    32768 B
  float*    selW   = (float*)(ws + 294912);         //    32768 B
  u16*      Xsel   = (u16*)(ws + 327680);           // 33554432 B
  u16*      WgT    = (u16*)(ws + 33882112ull);      // 22544384 B
  u16*      WuT    = (u16*)(ws + 56426496ull);      // 22544384 B
  u16*      WdT    = (u16*)(ws + 78970880ull);      // 22413312 B
  u16*      act    = (u16*)(ws + 101384192ull);     // 89653248 B

  hipMemsetAsync(d_out, 0, (size_t)N_TOK * HDIM * sizeof(float), stream);
  transpose_convert<<<dim3(172, 64), dim3(32, 8), 0, stream>>>(w_gate, 2048, DFF, WgT, 2048);
  transpose_convert<<<dim3(172, 64), dim3(32, 8), 0, stream>>>(w_up,   2048, DFF, WuT, 2048);
  transpose_convert<<<dim3(64, 171), dim3(32, 8), 0, stream>>>(w_down, DFF, 2048, WdT, DFF_PA);
  router_kernel<<<N_TOK / 4, 256, 0, stream>>>(x, rw, rb, SmT);
  select_topk<<<NEXP, 1024, 0, stream>>>(SmT, selTok, selW);
  gather_kernel<<<N_TOK, 256, 0, stream>>>(x, selTok, Xsel);
  gemm1_kernel<<<43 * 32, 512, 0, stream>>>(Xsel, WgT, WuT, b_gate, b_up, act);
  gemm2_kernel<<<8 * 32, 512, 0, stream>>>(act, WdT, b_down, selTok, selW, y);
}

// Round 3
// 911.044 us; speedup vs baseline: 1.1958x; 1.1958x over previous
//
#include <hip/hip_runtime.h>
#include <cstdint>
#include <cstddef>

#define N_TOK  8192
#define HDIM   2048
#define NEXP   8
#define KCAP   1024
#define DFF    5461
#define DFF_PB 5504   // padded rows for WgT/WuT (N of gemm1)
#define ACT_P  5504   // act row pitch / gemm2 K (multiple of 64)
#define NT1    (HDIM / 64)    // 32
#define NT2    (ACT_P / 64)   // 86

typedef unsigned short u16;
typedef short bf16x8 __attribute__((ext_vector_type(8)));
typedef float f32x4  __attribute__((ext_vector_type(4)));

__device__ __forceinline__ u16 f2bf(float f) {
  uint32_t u = __float_as_uint(f);
  uint32_t r = (u + 0x7FFFu + ((u >> 16) & 1u)) >> 16;
  return (u16)r;
}

__device__ __forceinline__ uint32_t rotl32(uint32_t v, int d) {
  return (v << d) | (v >> (32 - d));
}

// JAX threefry2x32, key = (0, 42), partitionable scheme: counter=(0,i), bits = x0^x1.
__device__ uint32_t threefry_bits(uint32_t idx) {
  const uint32_t ks0 = 0u, ks1 = 42u, ks2 = 0u ^ 42u ^ 0x1BD11BDAu;
  uint32_t x0 = 0u + ks0;
  uint32_t x1 = idx + ks1;
#define TFR(d) { x0 += x1; x1 = rotl32(x1, d); x1 ^= x0; }
  TFR(13) TFR(15) TFR(26) TFR(6)
  x0 += ks1; x1 += ks2 + 1u;
  TFR(17) TFR(29) TFR(16) TFR(24)
  x0 += ks2; x1 += ks0 + 2u;
  TFR(13) TFR(15) TFR(26) TFR(6)
  x0 += ks0; x1 += ks1 + 3u;
  TFR(17) TFR(29) TFR(16) TFR(24)
  x0 += ks1; x1 += ks2 + 4u;
  TFR(13) TFR(15) TFR(26) TFR(6)
  x0 += ks2; x1 += ks0 + 5u;
#undef TFR
  return x0 ^ x1;
}

// ---------------- router: clean_h + gumbel -> softmax, stored transposed [E][n_tok]
__global__ __launch_bounds__(256) void router_kernel(const float* __restrict__ x,
    const float* __restrict__ rw, const float* __restrict__ rb,
    float* __restrict__ SmT)
{
  const int lane = threadIdx.x & 63;
  const int wid  = threadIdx.x >> 6;
  const int t = blockIdx.x * 4 + wid;     // one token per wave
  const float* xr = x + (size_t)t * HDIM;
  float acc[8] = {0.f,0.f,0.f,0.f,0.f,0.f,0.f,0.f};
#pragma unroll
  for (int it = 0; it < HDIM / 64; ++it) {
    int h = lane + it * 64;
    float xv = xr[h];
    const float4* wp = (const float4*)(rw + h * 8);
    float4 w0 = wp[0], w1 = wp[1];
    acc[0] = fmaf(xv, w0.x, acc[0]);
    acc[1] = fmaf(xv, w0.y, acc[1]);
    acc[2] = fmaf(xv, w0.z, acc[2]);
    acc[3] = fmaf(xv, w0.w, acc[3]);
    acc[4] = fmaf(xv, w1.x, acc[4]);
    acc[5] = fmaf(xv, w1.y, acc[5]);
    acc[6] = fmaf(xv, w1.z, acc[6]);
    acc[7] = fmaf(xv, w1.w, acc[7]);
  }
#pragma unroll
  for (int m = 32; m >= 1; m >>= 1) {
#pragma unroll
    for (int e = 0; e < 8; ++e) acc[e] += __shfl_xor(acc[e], m, 64);
  }
  if (lane == 0) {
    float h[8];
#pragma unroll
    for (int e = 0; e < 8; ++e) {
      uint32_t bits = threefry_bits((uint32_t)(t * 8 + e));
      float u = __uint_as_float((bits >> 9) | 0x3f800000u) - 1.0f;
      u = fmaxf(u, 0.0f);
      float g = -logf(-logf(u + 1e-10f) + 1e-10f);
      h[e] = acc[e] + rb[e] + g;
    }
    float mx = h[0];
#pragma unroll
    for (int e = 1; e < 8; ++e) mx = fmaxf(mx, h[e]);
    float ex[8]; float s = 0.f;
#pragma unroll
    for (int e = 0; e < 8; ++e) { ex[e] = expf(h[e] - mx); s += ex[e]; }
#pragma unroll
    for (int e = 0; e < 8; ++e) SmT[e * N_TOK + t] = ex[e] / s;
  }
}

// ---------------- exact top-1024-of-8192 per expert via 4-pass radix select
__global__ __launch_bounds__(1024) void select_topk(const float* __restrict__ SmT,
    uint32_t* __restrict__ selTok, float* __restrict__ selW)
{
  const int e = blockIdx.x;
  const int tid = threadIdx.x;
  const float* v = SmT + (size_t)e * N_TOK;
  __shared__ uint32_t hist[256];
  __shared__ uint32_t sh_byte, sh_kk, sh_cnt, sh_eqc;
  uint32_t bitsv[8];
#pragma unroll
  for (int i = 0; i < 8; ++i) bitsv[i] = __float_as_uint(v[tid + i * 1024]);
  uint32_t prefix = 0;
  uint32_t kk = KCAP;
  for (int s = 3; s >= 0; --s) {
    if (tid < 256) hist[tid] = 0;
    __syncthreads();
    uint32_t himask = (s == 3) ? 0u : (0xFFFFFFFFu << ((s + 1) * 8));
#pragma unroll
    for (int i = 0; i < 8; ++i) {
      uint32_t b = bitsv[i];
      if ((b & himask) == prefix) atomicAdd(&hist[(b >> (s * 8)) & 255u], 1u);
    }
    __syncthreads();
    if (tid == 0) {
      uint32_t cum = 0; uint32_t bsel = 0, kn = kk;
      for (int b = 255; b >= 0; --b) {
        uint32_t c = hist[b];
        if (cum + c >= kk) { bsel = (uint32_t)b; kn = kk - cum; break; }
        cum += c;
      }
      sh_byte = bsel; sh_kk = kn;
    }
    __syncthreads();
    prefix |= sh_byte << (s * 8);
    kk = sh_kk;
  }
  const uint32_t T = prefix;
  const uint32_t need = kk;
  if (tid == 0) { sh_cnt = 0; sh_eqc = 0; }
  __syncthreads();
#pragma unroll
  for (int i = 0; i < 8; ++i) {
    uint32_t b = bitsv[i];
    if (b > T) {
      uint32_t p = atomicAdd(&sh_cnt, 1u);
      selTok[e * KCAP + p] = (uint32_t)(tid + i * 1024);
      selW[e * KCAP + p] = __uint_as_float(b);
    } else if (b == T) {
      atomicAdd(&sh_eqc, 1u);
    }
  }
  __syncthreads();
  if (sh_eqc == need) {
#pragma unroll
    for (int i = 0; i < 8; ++i) {
      if (bitsv[i] == T) {
        uint32_t p = atomicAdd(&sh_cnt, 1u);
        selTok[e * KCAP + p] = (uint32_t)(tid + i * 1024);
        selW[e * KCAP + p] = __uint_as_float(T);
      }
    }
  } else if (tid == 0) {
    uint32_t p = sh_cnt, rem = need;
    for (int t = 0; t < N_TOK && rem > 0u; ++t) {
      if (__float_as_uint(v[t]) == T) {
        selTok[e * KCAP + p] = (uint32_t)t;
        selW[e * KCAP + p] = __uint_as_float(T);
        ++p; --rem;
      }
    }
  }
}

// ---------------- inverse slot index: inv[e][tok] = slot (-1 if not chosen)
__global__ __launch_bounds__(256) void build_inv(const uint32_t* __restrict__ selTok,
    int* __restrict__ inv)
{
  int s = blockIdx.x * 256 + threadIdx.x;   // 0..8191
  inv[(s >> 10) * N_TOK + (int)selTok[s]] = s;
}

// ---------------- gather selected token rows, fp32 -> bf16
__global__ __launch_bounds__(256) void gather_kernel(const float* __restrict__ x,
    const uint32_t* __restrict__ selTok, u16* __restrict__ Xsel)
{
  const int slot = blockIdx.x;
  const int tid = threadIdx.x;
  const uint32_t tok = selTok[slot];
  const float4* src = (const float4*)(x + (size_t)tok * HDIM);
  float4 a = src[tid * 2], b = src[tid * 2 + 1];
  union { u16 h[8]; uint4 vv; } pk;
  pk.h[0] = f2bf(a.x); pk.h[1] = f2bf(a.y); pk.h[2] = f2bf(a.z); pk.h[3] = f2bf(a.w);
  pk.h[4] = f2bf(b.x); pk.h[5] = f2bf(b.y); pk.h[6] = f2bf(b.z); pk.h[7] = f2bf(b.w);
  ((uint4*)(Xsel + (size_t)slot * HDIM))[tid] = pk.vv;
}

// ---------------- transpose + fp32->bf16: out[j][i] = in[i][j], zero-padded
__global__ __launch_bounds__(256) void transpose_convert(const float* __restrict__ in,
    int rows_in, int cols_in, u16* __restrict__ out, int out_cols)
{
  __shared__ float tile[32][33];
  const int bi = blockIdx.y;
  const int bj = blockIdx.x;
  const int tx = threadIdx.x, ty = threadIdx.y;
#pragma unroll
  for (int t = 0; t < 4; ++t) {
    int r = bi * 32 + ty + t * 8, c = bj * 32 + tx;
    float vv = (r < rows_in && c < cols_in) ? in[(size_t)r * cols_in + c] : 0.0f;
    tile[ty + t * 8][tx] = vv;
  }
  __syncthreads();
#pragma unroll
  for (int t = 0; t < 4; ++t) {
    int oj = bj * 32 + ty + t * 8;
    int oi = bi * 32 + tx;
    out[(size_t)oj * out_cols + oi] = f2bf(tile[tx][ty + t * 8]);
  }
}

// ---------------- async global->LDS staging helper
#if defined(__has_builtin)
#  if __has_builtin(__builtin_amdgcn_global_load_lds)
#    define HAVE_GLD 1
#  endif
#endif
#ifdef HAVE_GLD
#define STG(gp, lp) __builtin_amdgcn_global_load_lds( \
    (const __attribute__((address_space(1))) void*)(gp), \
    (__attribute__((address_space(3))) void*)(lp), 16, 0, 0)
#define WAITV4() asm volatile("s_waitcnt vmcnt(4)" ::: "memory")
#define WAITV2() asm volatile("s_waitcnt vmcnt(2)" ::: "memory")
#define WAITV0() asm volatile("s_waitcnt vmcnt(0)" ::: "memory")
#else
#define STG(gp, lp) (*(bf16x8*)(lp) = *(const bf16x8*)(gp))
#define WAITV4() asm volatile("s_waitcnt vmcnt(0) lgkmcnt(0)" ::: "memory")
#define WAITV2() asm volatile("s_waitcnt vmcnt(0) lgkmcnt(0)" ::: "memory")
#define WAITV0() asm volatile("s_waitcnt vmcnt(0) lgkmcnt(0)" ::: "memory")
#endif
#define BAR()    __builtin_amdgcn_s_barrier()
#define SCHED0() __builtin_amdgcn_sched_barrier(0)
#define PRIO1()  __builtin_amdgcn_s_setprio(1)
#define PRIO0()  __builtin_amdgcn_s_setprio(0)
#define MFMA(a, b, c) __builtin_amdgcn_mfma_f32_16x16x32_bf16(a, b, c, 0, 0, 0)

// ======================================================================
// m201-style 4-phase K-loop, BK=64, 8 waves (2M x 4N), 1 block/CU (128 KiB).
// Consumption per K-tile: {A0,B0}@P0, {B1}@P1, {A1}@P2, {}@P3; staging of
// kt+1 in the same order, one half per phase (2 GLD16/thread/phase).
// Counted waits at END of P0/P1/P3, before the barrier (wait+barrier proves
// landing for ALL waves). Steady state vmcnt(4) leaves 2 half-tiles in
// flight. TAIL FIX (round-2): in the last K-tile no stages are issued, so
// outstanding is only 4 -> vmcnt(4) was a no-op and P1/P2 read un-landed
// LDS (the round-1 absmax failure). Last tile now uses vmcnt(2) at P0-end
// (lands B1-half) and vmcnt(0) at P1-end (lands A1-half).
// Swizzle: 16B chunk q of row r holds global chunk q^(r&7); frag rows are
// == fr (mod 8) -> ds_read_b128 conflict-free. Re-stage targets the other
// buffer of the pair (dbuf), >=4 barriers after its last read drained.
// ======================================================================

// GEMM1: act = silu(Xsel*WgT + bg) .* (Xsel*WuT + bu), bf16 out.
// Dual-B: Bg is "B half0", Bu is "B half1". Block tile 256M x 128N,
// wave tile 128M x 32N x {gate,up}. Grid 32bm x 43bn = 1376 = 8*172.
__global__ __launch_bounds__(512, 2) void gemm1_kernel(
    const u16* __restrict__ Xsel,  // [8192][2048] bf16
    const u16* __restrict__ WgT,   // [5504][2048] bf16 (N-major, K-contig)
    const u16* __restrict__ WuT,   // [5504][2048]
    const float* __restrict__ bg, const float* __restrict__ bu,
    u16* __restrict__ act)         // [8192][5504] bf16
{
  __shared__ u16 AL[2][2][8192];   // 64 KB  (dbuf x Mhalf x 128rows x 64K)
  __shared__ u16 GL[2][8192];      // 32 KB
  __shared__ u16 UL[2][8192];      // 32 KB

  const int id = blockIdx.x;                   // 1376 = 8 * 172
  const int wg = (id & 7) * 172 + (id >> 3);   // XCD-chunked bijection
  const int bm = wg & 31;                      // 0..31
  const int bn = wg >> 5;                      // 0..42

  const int tid = threadIdx.x;
  const int lane = tid & 63, wid = tid >> 6;
  const int wm = wid >> 2, wn = wid & 3;
  const int fr = lane & 15, ck = lane >> 4;
  const int sw0 = (ck ^ (fr & 7)) * 8;         // u16 offset of ks=0 chunk
  const int sw1 = sw0 ^ 32;                    // ks=1 chunk (^4 chunks)
  const int rA = (wm * 64 + fr) * 64;
  const int rB = (wn * 32 + fr) * 64;

  // staging: thread covers LDS 16B-slots {tid, tid+512} -> rows sr, sr+64,
  // both at swizzled global chunk sq (since 64 ≡ 0 mod 8).
  const int sr = tid >> 3;
  const int sq = (tid & 7) ^ (sr & 7);
  const u16* aS0 = Xsel + (size_t)(bm * 256 + sr) * HDIM + sq * 8;
  const u16* aS1 = aS0 + (size_t)128 * HDIM;
  const u16* gS  = WgT + (size_t)(bn * 128 + sr) * HDIM + sq * 8;
  const u16* uS  = WuT + (size_t)(bn * 128 + sr) * HDIM + sq * 8;

#define ST_A0(kt) { u16* d = &AL[(kt)&1][0][tid*8]; \
    STG(aS0 + (kt)*64, d); STG(aS0 + (kt)*64 + (size_t)64*HDIM, d + 4096); }
#define ST_A1(kt) { u16* d = &AL[(kt)&1][1][tid*8]; \
    STG(aS1 + (kt)*64, d); STG(aS1 + (kt)*64 + (size_t)64*HDIM, d + 4096); }
#define ST_G(kt) { u16* d = &GL[(kt)&1][tid*8]; \
    STG(gS + (kt)*64, d); STG(gS + (kt)*64 + (size_t)64*HDIM, d + 4096); }
#define ST_U(kt) { u16* d = &UL[(kt)&1][tid*8]; \
    STG(uS + (kt)*64, d); STG(uS + (kt)*64 + (size_t)64*HDIM, d + 4096); }

  f32x4 accg[8][2], accu[8][2];
  const f32x4 z4 = {0.f, 0.f, 0.f, 0.f};
#pragma unroll
  for (int i = 0; i < 8; ++i)
#pragma unroll
    for (int n = 0; n < 2; ++n) { accg[i][n] = z4; accu[i][n] = z4; }

  bf16x8 af[4][2], bgf[2][2], buf[2][2];

  // prologue: stage kt0 halves in consumption order; A0+G landed after wait.
  ST_A0(0) ST_G(0) ST_U(0) ST_A1(0)
  WAITV4(); BAR();

  for (int kt = 0; kt < NT1; ++kt) {
    const u16* A0 = AL[kt & 1][0];
    const u16* A1 = AL[kt & 1][1];
    const u16* G  = GL[kt & 1];
    const u16* U  = UL[kt & 1];
    const int st = (kt + 1 < NT1);
    // ---- P0: read A0 frags + Bg frags; stage A0(kt+1); 16 MFMA (gate, m0-3)
#pragma unroll
    for (int i = 0; i < 4; ++i) {
      af[i][0] = *(const bf16x8*)&A0[rA + i * 1024 + sw0];
      af[i][1] = *(const bf16x8*)&A0[rA + i * 1024 + sw1];
    }
#pragma unroll
    for (int n = 0; n < 2; ++n) {
      bgf[n][0] = *(const bf16x8*)&G[rB + n * 1024 + sw0];
      bgf[n][1] = *(const bf16x8*)&G[rB + n * 1024 + sw1];
    }
    if (st) ST_A0(kt + 1)
    BAR(); SCHED0();
    PRIO1();
#pragma unroll
    for (int ks = 0; ks < 2; ++ks)
#pragma unroll
      for (int i = 0; i < 4; ++i)
#pragma unroll
        for (int n = 0; n < 2; ++n)
          accg[i][n] = MFMA(af[i][ks], bgf[n][ks], accg[i][n]);
    PRIO0();
    if (st) { WAITV4(); } else { WAITV2(); }
    BAR();
    // ---- P1: read Bu frags; stage G(kt+1); 16 MFMA (up, m0-3)
#pragma unroll
    for (int n = 0; n < 2; ++n) {
      buf[n][0] = *(const bf16x8*)&U[rB + n * 1024 + sw0];
      buf[n][1] = *(const bf16x8*)&U[rB + n * 1024 + sw1];
    }
    if (st) ST_G(kt + 1)
    BAR(); SCHED0();
    PRIO1();
#pragma unroll
    for (int ks = 0; ks < 2; ++ks)
#pragma unroll
      for (int i = 0; i < 4; ++i)
#pragma unroll
        for (int n = 0; n < 2; ++n)
          accu[i][n] = MFMA(af[i][ks], buf[n][ks], accu[i][n]);
    PRIO0();
    if (st) { WAITV4(); } else { WAITV0(); }
    BAR();
    // ---- P2: read A1 frags; stage U(kt+1); 16 MFMA (gate, m4-7)
#pragma unroll
    for (int i = 0; i < 4; ++i) {
      af[i][0] = *(const bf16x8*)&A1[rA + i * 1024 + sw0];
      af[i][1] = *(const bf16x8*)&A1[rA + i * 1024 + sw1];
    }
    if (st) ST_U(kt + 1)
    BAR(); SCHED0();
    PRIO1();
#pragma unroll
    for (int ks = 0; ks < 2; ++ks)
#pragma unroll
      for (int i = 0; i < 4; ++i)
#pragma unroll
        for (int n = 0; n < 2; ++n)
          accg[4 + i][n] = MFMA(af[i][ks], bgf[n][ks], accg[4 + i][n]);
    PRIO0();
    // ---- P3: stage A1(kt+1); 16 MFMA (up, m4-7); boundary wait
    if (st) ST_A1(kt + 1)
    PRIO1();
#pragma unroll
    for (int ks = 0; ks < 2; ++ks)
#pragma unroll
      for (int i = 0; i < 4; ++i)
#pragma unroll
        for (int n = 0; n < 2; ++n)
          accu[4 + i][n] = MFMA(af[i][ks], buf[n][ks], accu[4 + i][n]);
    PRIO0();
    WAITV4();
    BAR();
  }

  // epilogue: silu(g+bg)*(u+bu) -> bf16; pad cols [DFF, ACT_P) get 0
#pragma unroll
  for (int f = 0; f < 8; ++f) {
    const int rbase = bm * 256 + (f >> 2) * 128 + wm * 64 + (f & 3) * 16 + ck * 4;
#pragma unroll
    for (int v = 0; v < 4; ++v) {
      u16* arow = act + (size_t)(rbase + v) * ACT_P;
#pragma unroll
      for (int n = 0; n < 2; ++n) {
        const int col = bn * 128 + wn * 32 + n * 16 + fr;
        u16 ov = 0;
        if (col < DFF) {
          float gv = accg[f][n][v] + bg[col];
          float uv = accu[f][n][v] + bu[col];
          ov = f2bf((gv / (1.0f + expf(-gv))) * uv);
        }
        arow[col] = ov;
      }
    }
  }
#undef ST_A0
#undef ST_A1
#undef ST_G
#undef ST_U
}

// GEMM2: Yslot[slot] = selW[slot] * (act[slot]*WdT + bd)  (dense, no atomics)
// Block tile 256M x 256N, wave tile 128M x 64N. Grid 32bm x 8bn = 256 = 8*32.
__global__ __launch_bounds__(512, 2) void gemm2_kernel(
    const u16* __restrict__ act,   // [8192][5504] bf16
    const u16* __restrict__ WdT,   // [2048][5504] bf16
    const float* __restrict__ bd,  // [2048]
    const float* __restrict__ selW,
    float* __restrict__ Yslot)     // [8192][2048] fp32 slot-major
{
  __shared__ u16 AL[2][2][8192];   // 64 KB
  __shared__ u16 BL[2][2][8192];   // 64 KB

  const int id = blockIdx.x;                  // 256 = 8 * 32
  const int wg = (id & 7) * 32 + (id >> 3);
  const int bm = wg & 31, bn = wg >> 5;

  const int tid = threadIdx.x;
  const int lane = tid & 63, wid = tid >> 6;
  const int wm = wid >> 2, wn = wid & 3;
  const int fr = lane & 15, ck = lane >> 4;
  const int sw0 = (ck ^ (fr & 7)) * 8;
  const int sw1 = sw0 ^ 32;
  const int rA = (wm * 64 + fr) * 64;
  const int rB = (wn * 32 + fr) * 64;

  const int sr = tid >> 3;
  const int sq = (tid & 7) ^ (sr & 7);
  const u16* aS0 = act + (size_t)(bm * 256 + sr) * ACT_P + sq * 8;
  const u16* aS1 = aS0 + (size_t)128 * ACT_P;
  const u16* bS0 = WdT + (size_t)(bn * 256 + sr) * ACT_P + sq * 8;
  const u16* bS1 = bS0 + (size_t)128 * ACT_P;

#define ST_A0(kt) { u16* d = &AL[(kt)&1][0][tid*8]; \
    STG(aS0 + (kt)*64, d); STG(aS0 + (kt)*64 + (size_t)64*ACT_P, d + 4096); }
#define ST_A1(kt) { u16* d = &AL[(kt)&1][1][tid*8]; \
    STG(aS1 + (kt)*64, d); STG(aS1 + (kt)*64 + (size_t)64*ACT_P, d + 4096); }
#define ST_B0(kt) { u16* d = &BL[(kt)&1][0][tid*8]; \
    STG(bS0 + (kt)*64, d); STG(bS0 + (kt)*64 + (size_t)64*ACT_P, d + 4096); }
#define ST_B1(kt) { u16* d = &BL[(kt)&1][1][tid*8]; \
    STG(bS1 + (kt)*64, d); STG(bS1 + (kt)*64 + (size_t)64*ACT_P, d + 4096); }

  f32x4 acc[8][4];
  const f32x4 z4 = {0.f, 0.f, 0.f, 0.f};
#pragma unroll
  for (int i = 0; i < 8; ++i)
#pragma unroll
    for (int n = 0; n < 4; ++n) acc[i][n] = z4;

  bf16x8 af[4][2], b0[2][2], b1[2][2];

  ST_A0(0) ST_B0(0) ST_B1(0) ST_A1(0)
  WAITV4(); BAR();

  for (int kt = 0; kt < NT2; ++kt) {
    const u16* A0 = AL[kt & 1][0];
    const u16* A1 = AL[kt & 1][1];
    const u16* B0 = BL[kt & 1][0];
    const u16* B1 = BL[kt & 1][1];
    const int st = (kt + 1 < NT2);
    // ---- P0
#pragma unroll
    for (int i = 0; i < 4; ++i) {
      af[i][0] = *(const bf16x8*)&A0[rA + i * 1024 + sw0];
      af[i][1] = *(const bf16x8*)&A0[rA + i * 1024 + sw1];
    }
#pragma unroll
    for (int n = 0; n < 2; ++n) {
      b0[n][0] = *(const bf16x8*)&B0[rB + n * 1024 + sw0];
      b0[n][1] = *(const bf16x8*)&B0[rB + n * 1024 + sw1];
    }
    if (st) ST_A0(kt + 1)
    BAR(); SCHED0();
    PRIO1();
#pragma unroll
    for (int ks = 0; ks < 2; ++ks)
#pragma unroll
      for (int i = 0; i < 4; ++i)
#pragma unroll
        for (int n = 0; n < 2; ++n)
          acc[i][n] = MFMA(af[i][ks], b0[n][ks], acc[i][n]);
    PRIO0();
    if (st) { WAITV4(); } else { WAITV2(); }
    BAR();
    // ---- P1
#pragma unroll
    for (int n = 0; n < 2; ++n) {
      b1[n][0] = *(const bf16x8*)&B1[rB + n * 1024 + sw0];
      b1[n][1] = *(const bf16x8*)&B1[rB + n * 1024 + sw1];
    }
    if (st) ST_B0(kt + 1)
    BAR(); SCHED0();
    PRIO1();
#pragma unroll
    for (int ks = 0; ks < 2; ++ks)
#pragma unroll
      for (int i = 0; i < 4; ++i)
#pragma unroll
        for (int n = 0; n < 2; ++n)
          acc[i][2 + n] = MFMA(af[i][ks], b1[n][ks], acc[i][2 + n]);
    PRIO0();
    if (st) { WAITV4(); } else { WAITV0(); }
    BAR();
    // ---- P2
#pragma unroll
    for (int i = 0; i < 4; ++i) {
      af[i][0] = *(const bf16x8*)&A1[rA + i * 1024 + sw0];
      af[i][1] = *(const bf16x8*)&A1[rA + i * 1024 + sw1];
    }
    if (st) ST_B1(kt + 1)
    BAR(); SCHED0();
    PRIO1();
#pragma unroll
    for (int ks = 0; ks < 2; ++ks)
#pragma unroll
      for (int i = 0; i < 4; ++i)
#pragma unroll
        for (int n = 0; n < 2; ++n)
          acc[4 + i][n] = MFMA(af[i][ks], b0[n][ks], acc[4 + i][n]);
    PRIO0();
    // ---- P3
    if (st) ST_A1(kt + 1)
    PRIO1();
#pragma unroll
    for (int ks = 0; ks < 2; ++ks)
#pragma unroll
      for (int i = 0; i < 4; ++i)
#pragma unroll
        for (int n = 0; n < 2; ++n)
          acc[4 + i][2 + n] = MFMA(af[i][ks], b1[n][ks], acc[4 + i][2 + n]);
    PRIO0();
    WAITV4();
    BAR();
  }

  // epilogue: weighted dense store (no atomics)
#pragma unroll
  for (int f = 0; f < 8; ++f) {
    const int rbase = bm * 256 + (f >> 2) * 128 + wm * 64 + (f & 3) * 16 + ck * 4;
#pragma unroll
    for (int v = 0; v < 4; ++v) {
      const int srow = rbase + v;
      const float w = selW[srow];
      float* yrow = Yslot + (size_t)srow * HDIM;
#pragma unroll
      for (int n = 0; n < 4; ++n) {
        const int col = bn * 256 + (n >> 1) * 128 + wn * 32 + (n & 1) * 16 + fr;
        yrow[col] = w * (acc[f][n][v] + bd[col]);
      }
    }
  }
#undef ST_A0
#undef ST_A1
#undef ST_B0
#undef ST_B1
}

// ---------------- scatter: y[tok] = sum over experts of Yslot[inv[e][tok]]
__global__ __launch_bounds__(256) void scatter_kernel(const float* __restrict__ Yslot,
    const int* __restrict__ inv, float* __restrict__ y)
{
  const int t = blockIdx.x;
  const int c = threadIdx.x * 8;
  float4 a0 = {0.f,0.f,0.f,0.f}, a1 = {0.f,0.f,0.f,0.f};
#pragma unroll
  for (int e = 0; e < 8; ++e) {
    const int s = inv[e * N_TOK + t];
    if (s >= 0) {
      const float4* p = (const float4*)(Yslot + (size_t)s * HDIM + c);
      float4 v0 = p[0], v1 = p[1];
      a0.x += v0.x; a0.y += v0.y; a0.z += v0.z; a0.w += v0.w;
      a1.x += v1.x; a1.y += v1.y; a1.z += v1.z; a1.w += v1.w;
    }
  }
  float4* yp = (float4*)(y + (size_t)t * HDIM + c);
  yp[0] = a0; yp[1] = a1;
}

extern "C" void kernel_launch(void* const* d_in, const int* in_sizes, int n_in,
                              void* d_out, int out_size, void* d_ws, size_t ws_size,
                              hipStream_t stream) {
  const float* x      = (const float*)d_in[0];
  const float* rw     = (const float*)d_in[1];
  const float* rb     = (const float*)d_in[2];
  const float* w_gate = (const float*)d_in[3];
  const float* b_gate = (const float*)d_in[4];
  const float* w_up   = (const float*)d_in[5];
  const float* b_up   = (const float*)d_in[6];
  const float* w_down = (const float*)d_in[7];
  const float* b_down = (const float*)d_in[8];
  float* y = (float*)d_out;

  // Workspace layout (max end 180,158,464 B; aliasing by lifetime):
  //  [0,32K)        selTok          (live: select..gather)
  //  [32K,64K)      selW            (live through gemm2)
  //  [64K,320K)     inv             (live through scatter)
  //  [320K,90.5M)   act [8192][5504] bf16 (gemm1 -> gemm2)
  //  [90.5M,124.06M) Xsel [8192][2048] bf16 (gather->gemm1); WdT aliases
  //                 here (transposed AFTER gemm1, read by gemm2)
  //  [113.05M,180.2M) Yslot [8192][2048] f32 (gemm2->scatter); overlays
  //                 SmT/WgT/WuT which are dead after gemm1
  //  [124.06M,124.3M) SmT (router->select)
  //  [124.3M,146.9M)  WgT ; [146.9M,169.4M) WuT (transpose->gemm1)
  uint8_t* ws = (uint8_t*)d_ws;
  uint32_t* selTok = (uint32_t*)(ws + 0);
  float*    selW   = (float*)(ws + 32768);
  int*      inv    = (int*)(ws + 65536);
  u16*      act    = (u16*)(ws + 327680);
  u16*      Xsel   = (u16*)(ws + 90505216ull);
  u16*      WdT    = (u16*)(ws + 90505216ull);
  float*    Yslot  = (float*)(ws + 113049600ull);
  float*    SmT    = (float*)(ws + 124059648ull);
  u16*      WgT    = (u16*)(ws + 124321792ull);
  u16*      WuT    = (u16*)(ws + 146866176ull);

  hipMemsetAsync(inv, 0xFF, NEXP * N_TOK * sizeof(int), stream);
  transpose_convert<<<dim3(172, 64), dim3(32, 8), 0, stream>>>(w_gate, 2048, DFF, WgT, 2048);
  transpose_convert<<<dim3(172, 64), dim3(32, 8), 0, stream>>>(w_up,   2048, DFF, WuT, 2048);
  router_kernel<<<N_TOK / 4, 256, 0, stream>>>(x, rw, rb, SmT);
  select_topk<<<NEXP, 1024, 0, stream>>>(SmT, selTok, selW);
  build_inv<<<N_TOK / 256, 256, 0, stream>>>(selTok, inv);
  gather_kernel<<<N_TOK, 256, 0, stream>>>(x, selTok, Xsel);
  gemm1_kernel<<<43 * 32, 512, 0, stream>>>(Xsel, WgT, WuT, b_gate, b_up, act);
  transpose_convert<<<dim3(64, 172), dim3(32, 8), 0, stream>>>(w_down, DFF, 2048, WdT, ACT_P);
  gemm2_kernel<<<8 * 32, 512, 0, stream>>>(act, WdT, b_down, selW, Yslot);
  scatter_kernel<<<N_TOK, 256, 0, stream>>>(Yslot, inv, y);
}

// Round 4
// 874.684 us; speedup vs baseline: 1.2455x; 1.0416x over previous
//
#include <hip/hip_runtime.h>
#include <cstdint>
#include <cstddef>

#define N_TOK  8192
#define HDIM   2048
#define NEXP   8
#define KCAP   1024
#define DFF    5461
#define DFF_PB 5504   // padded rows for WgT/WuT (N of gemm1)
#define ACT_P  5504   // act row pitch / gemm2 K (multiple of 64)
#define NT1    (HDIM / 64)    // 32
#define NT2    (ACT_P / 64)   // 86

typedef unsigned short u16;
typedef short bf16x8 __attribute__((ext_vector_type(8)));
typedef float f32x4  __attribute__((ext_vector_type(4)));

__device__ __forceinline__ u16 f2bf(float f) {
  uint32_t u = __float_as_uint(f);
  uint32_t r = (u + 0x7FFFu + ((u >> 16) & 1u)) >> 16;
  return (u16)r;
}

__device__ __forceinline__ uint32_t rotl32(uint32_t v, int d) {
  return (v << d) | (v >> (32 - d));
}

// JAX threefry2x32, key = (0, 42), partitionable scheme: counter=(0,i), bits = x0^x1.
__device__ uint32_t threefry_bits(uint32_t idx) {
  const uint32_t ks0 = 0u, ks1 = 42u, ks2 = 0u ^ 42u ^ 0x1BD11BDAu;
  uint32_t x0 = 0u + ks0;
  uint32_t x1 = idx + ks1;
#define TFR(d) { x0 += x1; x1 = rotl32(x1, d); x1 ^= x0; }
  TFR(13) TFR(15) TFR(26) TFR(6)
  x0 += ks1; x1 += ks2 + 1u;
  TFR(17) TFR(29) TFR(16) TFR(24)
  x0 += ks2; x1 += ks0 + 2u;
  TFR(13) TFR(15) TFR(26) TFR(6)
  x0 += ks0; x1 += ks1 + 3u;
  TFR(17) TFR(29) TFR(16) TFR(24)
  x0 += ks1; x1 += ks2 + 4u;
  TFR(13) TFR(15) TFR(26) TFR(6)
  x0 += ks2; x1 += ks0 + 5u;
#undef TFR
  return x0 ^ x1;
}

// ---------------- router: clean_h + gumbel -> softmax, stored transposed [E][n_tok]
__global__ __launch_bounds__(256) void router_kernel(const float* __restrict__ x,
    const float* __restrict__ rw, const float* __restrict__ rb,
    float* __restrict__ SmT)
{
  const int lane = threadIdx.x & 63;
  const int wid  = threadIdx.x >> 6;
  const int t = blockIdx.x * 4 + wid;     // one token per wave
  const float* xr = x + (size_t)t * HDIM;
  float acc[8] = {0.f,0.f,0.f,0.f,0.f,0.f,0.f,0.f};
#pragma unroll
  for (int it = 0; it < HDIM / 64; ++it) {
    int h = lane + it * 64;
    float xv = xr[h];
    const float4* wp = (const float4*)(rw + h * 8);
    float4 w0 = wp[0], w1 = wp[1];
    acc[0] = fmaf(xv, w0.x, acc[0]);
    acc[1] = fmaf(xv, w0.y, acc[1]);
    acc[2] = fmaf(xv, w0.z, acc[2]);
    acc[3] = fmaf(xv, w0.w, acc[3]);
    acc[4] = fmaf(xv, w1.x, acc[4]);
    acc[5] = fmaf(xv, w1.y, acc[5]);
    acc[6] = fmaf(xv, w1.z, acc[6]);
    acc[7] = fmaf(xv, w1.w, acc[7]);
  }
#pragma unroll
  for (int m = 32; m >= 1; m >>= 1) {
#pragma unroll
    for (int e = 0; e < 8; ++e) acc[e] += __shfl_xor(acc[e], m, 64);
  }
  if (lane == 0) {
    float h[8];
#pragma unroll
    for (int e = 0; e < 8; ++e) {
      uint32_t bits = threefry_bits((uint32_t)(t * 8 + e));
      float u = __uint_as_float((bits >> 9) | 0x3f800000u) - 1.0f;
      u = fmaxf(u, 0.0f);
      float g = -logf(-logf(u + 1e-10f) + 1e-10f);
      h[e] = acc[e] + rb[e] + g;
    }
    float mx = h[0];
#pragma unroll
    for (int e = 1; e < 8; ++e) mx = fmaxf(mx, h[e]);
    float ex[8]; float s = 0.f;
#pragma unroll
    for (int e = 0; e < 8; ++e) { ex[e] = expf(h[e] - mx); s += ex[e]; }
#pragma unroll
    for (int e = 0; e < 8; ++e) SmT[e * N_TOK + t] = ex[e] / s;
  }
}

// ---------------- exact top-1024-of-8192 per expert via 4-pass radix select
__global__ __launch_bounds__(1024) void select_topk(const float* __restrict__ SmT,
    uint32_t* __restrict__ selTok, float* __restrict__ selW)
{
  const int e = blockIdx.x;
  const int tid = threadIdx.x;
  const float* v = SmT + (size_t)e * N_TOK;
  __shared__ uint32_t hist[256];
  __shared__ uint32_t sh_byte, sh_kk, sh_cnt, sh_eqc;
  uint32_t bitsv[8];
#pragma unroll
  for (int i = 0; i < 8; ++i) bitsv[i] = __float_as_uint(v[tid + i * 1024]);
  uint32_t prefix = 0;
  uint32_t kk = KCAP;
  for (int s = 3; s >= 0; --s) {
    if (tid < 256) hist[tid] = 0;
    __syncthreads();
    uint32_t himask = (s == 3) ? 0u : (0xFFFFFFFFu << ((s + 1) * 8));
#pragma unroll
    for (int i = 0; i < 8; ++i) {
      uint32_t b = bitsv[i];
      if ((b & himask) == prefix) atomicAdd(&hist[(b >> (s * 8)) & 255u], 1u);
    }
    __syncthreads();
    if (tid == 0) {
      uint32_t cum = 0; uint32_t bsel = 0, kn = kk;
      for (int b = 255; b >= 0; --b) {
        uint32_t c = hist[b];
        if (cum + c >= kk) { bsel = (uint32_t)b; kn = kk - cum; break; }
        cum += c;
      }
      sh_byte = bsel; sh_kk = kn;
    }
    __syncthreads();
    prefix |= sh_byte << (s * 8);
    kk = sh_kk;
  }
  const uint32_t T = prefix;
  const uint32_t need = kk;
  if (tid == 0) { sh_cnt = 0; sh_eqc = 0; }
  __syncthreads();
#pragma unroll
  for (int i = 0; i < 8; ++i) {
    uint32_t b = bitsv[i];
    if (b > T) {
      uint32_t p = atomicAdd(&sh_cnt, 1u);
      selTok[e * KCAP + p] = (uint32_t)(tid + i * 1024);
      selW[e * KCAP + p] = __uint_as_float(b);
    } else if (b == T) {
      atomicAdd(&sh_eqc, 1u);
    }
  }
  __syncthreads();
  if (sh_eqc == need) {
#pragma unroll
    for (int i = 0; i < 8; ++i) {
      if (bitsv[i] == T) {
        uint32_t p = atomicAdd(&sh_cnt, 1u);
        selTok[e * KCAP + p] = (uint32_t)(tid + i * 1024);
        selW[e * KCAP + p] = __uint_as_float(T);
      }
    }
  } else if (tid == 0) {
    uint32_t p = sh_cnt, rem = need;
    for (int t = 0; t < N_TOK && rem > 0u; ++t) {
      if (__float_as_uint(v[t]) == T) {
        selTok[e * KCAP + p] = (uint32_t)t;
        selW[e * KCAP + p] = __uint_as_float(T);
        ++p; --rem;
      }
    }
  }
}

// ---------------- inverse slot index: inv[e][tok] = slot (-1 if not chosen)
__global__ __launch_bounds__(256) void build_inv(const uint32_t* __restrict__ selTok,
    int* __restrict__ inv)
{
  int s = blockIdx.x * 256 + threadIdx.x;   // 0..8191
  inv[(s >> 10) * N_TOK + (int)selTok[s]] = s;
}

// ---------------- gather selected token rows, fp32 -> bf16
__global__ __launch_bounds__(256) void gather_kernel(const float* __restrict__ x,
    const uint32_t* __restrict__ selTok, u16* __restrict__ Xsel)
{
  const int slot = blockIdx.x;
  const int tid = threadIdx.x;
  const uint32_t tok = selTok[slot];
  const float4* src = (const float4*)(x + (size_t)tok * HDIM);
  float4 a = src[tid * 2], b = src[tid * 2 + 1];
  union { u16 h[8]; uint4 vv; } pk;
  pk.h[0] = f2bf(a.x); pk.h[1] = f2bf(a.y); pk.h[2] = f2bf(a.z); pk.h[3] = f2bf(a.w);
  pk.h[4] = f2bf(b.x); pk.h[5] = f2bf(b.y); pk.h[6] = f2bf(b.z); pk.h[7] = f2bf(b.w);
  ((uint4*)(Xsel + (size_t)slot * HDIM))[tid] = pk.vv;
}

// ---------------- transpose + fp32->bf16: out[j][i] = in[i][j], zero-padded
__global__ __launch_bounds__(256) void transpose_convert(const float* __restrict__ in,
    int rows_in, int cols_in, u16* __restrict__ out, int out_cols)
{
  __shared__ float tile[32][33];
  const int bi = blockIdx.y;
  const int bj = blockIdx.x;
  const int tx = threadIdx.x, ty = threadIdx.y;
#pragma unroll
  for (int t = 0; t < 4; ++t) {
    int r = bi * 32 + ty + t * 8, c = bj * 32 + tx;
    float vv = (r < rows_in && c < cols_in) ? in[(size_t)r * cols_in + c] : 0.0f;
    tile[ty + t * 8][tx] = vv;
  }
  __syncthreads();
#pragma unroll
  for (int t = 0; t < 4; ++t) {
    int oj = bj * 32 + ty + t * 8;
    int oi = bi * 32 + tx;
    out[(size_t)oj * out_cols + oi] = f2bf(tile[tx][ty + t * 8]);
  }
}

// ---------------- async global->LDS staging helper
#if defined(__has_builtin)
#  if __has_builtin(__builtin_amdgcn_global_load_lds)
#    define HAVE_GLD 1
#  endif
#endif
#ifdef HAVE_GLD
#define STG(gp, lp) __builtin_amdgcn_global_load_lds( \
    (const __attribute__((address_space(1))) void*)(gp), \
    (__attribute__((address_space(3))) void*)(lp), 16, 0, 0)
#define WAITV6() asm volatile("s_waitcnt vmcnt(6)" ::: "memory")
#define WAITV4() asm volatile("s_waitcnt vmcnt(4)" ::: "memory")
#define WAITV2() asm volatile("s_waitcnt vmcnt(2)" ::: "memory")
#define WAITV0() asm volatile("s_waitcnt vmcnt(0)" ::: "memory")
#else
#define STG(gp, lp) (*(bf16x8*)(lp) = *(const bf16x8*)(gp))
#define WAITV6() asm volatile("s_waitcnt vmcnt(0) lgkmcnt(0)" ::: "memory")
#define WAITV4() asm volatile("s_waitcnt vmcnt(0) lgkmcnt(0)" ::: "memory")
#define WAITV2() asm volatile("s_waitcnt vmcnt(0) lgkmcnt(0)" ::: "memory")
#define WAITV0() asm volatile("s_waitcnt vmcnt(0) lgkmcnt(0)" ::: "memory")
#endif
#define BAR()    __builtin_amdgcn_s_barrier()
#define SCHED0() __builtin_amdgcn_sched_barrier(0)
#define PRIO1()  __builtin_amdgcn_s_setprio(1)
#define PRIO0()  __builtin_amdgcn_s_setprio(0)
#define MFMA(a, b, c) __builtin_amdgcn_mfma_f32_16x16x32_bf16(a, b, c, 0, 0, 0)

// ======================================================================
// 3-phase K-loop (r4), BK=64, 8 waves (2M x 4N), 1 block/CU (128 KiB LDS).
// Consumption per tile: {A0,B0}@P0, {B1}@P1, {A1}@P2.
// Staging of kt+1: P0: A0' (2 loads/thr); P1: B0'+B1' (4); P2: A1' (2).
// Waits at phase END before the barrier (per-wave vmcnt + barrier ==
// all-waves landed). Steady state: endP0 vmcnt(4) lands B1(kt) [gap 3
// phases]; endP1 vmcnt(6) lands A1(kt) [gap 3]; endP2 vmcnt(4) lands
// A0,B0(kt+1) [gap 3]. Tail (st==0, nothing staged): endP0 vmcnt(2),
// endP1 vmcnt(0), endP2's vmcnt(4) harmless no-op.
// Only ONE barrier per phase (3/tile): WAR re-stage hazards are >=3
// barriers apart; ordering across phases is anchored by the asm-wait
// "memory" clobbers + sched_barrier(0) after each s_barrier.
// Swizzle: 16B chunk q of row r holds global chunk q^(r&7); frag rows
// == fr (mod 8) -> ds_read_b128 conflict-free.
// ======================================================================

// GEMM1: act = silu(Xsel*WgT + bg) .* (Xsel*WuT + bu), bf16 out.
// Dual-B: Bg is "B0", Bu is "B1". Block tile 256M x 128N.
// XCD mapping (r4): bm-resident -- xcd owns 4 bm values, bn sweeps
// fastest => A slice (4 MB) L2-resident, B panels stream once per XCD.
__global__ __launch_bounds__(512, 2) void gemm1_kernel(
    const u16* __restrict__ Xsel,  // [8192][2048] bf16
    const u16* __restrict__ WgT,   // [5504][2048] bf16 (N-major, K-contig)
    const u16* __restrict__ WuT,   // [5504][2048]
    const float* __restrict__ bg, const float* __restrict__ bu,
    u16* __restrict__ act)         // [8192][5504] bf16
{
  __shared__ u16 AL[2][2][8192];   // 64 KB  (dbuf x Mhalf x 128rows x 64K)
  __shared__ u16 GL[2][8192];      // 32 KB
  __shared__ u16 UL[2][8192];      // 32 KB

  const int id = blockIdx.x;                   // 1376 = 8 * 172
  const int xcd = id & 7;
  const int r = id >> 3;                       // 0..171
  const int bm = xcd * 4 + (r & 3);            // 4 bm per XCD (A L2-resident)
  const int bn = r >> 2;                       // 0..42, sweeps fastest

  const int tid = threadIdx.x;
  const int lane = tid & 63, wid = tid >> 6;
  const int wm = wid >> 2, wn = wid & 3;
  const int fr = lane & 15, ck = lane >> 4;
  const int sw0 = (ck ^ (fr & 7)) * 8;         // u16 offset of ks=0 chunk
  const int sw1 = sw0 ^ 32;                    // ks=1 chunk (^4 chunks)
  const int rA = (wm * 64 + fr) * 64;
  const int rB = (wn * 32 + fr) * 64;

  // staging: thread covers LDS 16B-slots {tid, tid+512} -> rows sr, sr+64,
  // both at swizzled global chunk sq (since 64 ≡ 0 mod 8).
  const int sr = tid >> 3;
  const int sq = (tid & 7) ^ (sr & 7);
  const u16* aS0 = Xsel + (size_t)(bm * 256 + sr) * HDIM + sq * 8;
  const u16* aS1 = aS0 + (size_t)128 * HDIM;
  const u16* gS  = WgT + (size_t)(bn * 128 + sr) * HDIM + sq * 8;
  const u16* uS  = WuT + (size_t)(bn * 128 + sr) * HDIM + sq * 8;

#define ST_A0(kt) { u16* d = &AL[(kt)&1][0][tid*8]; \
    STG(aS0 + (kt)*64, d); STG(aS0 + (kt)*64 + (size_t)64*HDIM, d + 4096); }
#define ST_A1(kt) { u16* d = &AL[(kt)&1][1][tid*8]; \
    STG(aS1 + (kt)*64, d); STG(aS1 + (kt)*64 + (size_t)64*HDIM, d + 4096); }
#define ST_G(kt) { u16* d = &GL[(kt)&1][tid*8]; \
    STG(gS + (kt)*64, d); STG(gS + (kt)*64 + (size_t)64*HDIM, d + 4096); }
#define ST_U(kt) { u16* d = &UL[(kt)&1][tid*8]; \
    STG(uS + (kt)*64, d); STG(uS + (kt)*64 + (size_t)64*HDIM, d + 4096); }

  f32x4 accg[8][2], accu[8][2];
  const f32x4 z4 = {0.f, 0.f, 0.f, 0.f};
#pragma unroll
  for (int i = 0; i < 8; ++i)
#pragma unroll
    for (int n = 0; n < 2; ++n) { accg[i][n] = z4; accu[i][n] = z4; }

  bf16x8 af[4][2], bgf[2][2], buf[2][2];

  // prologue: stage tile0 in issue order A0,G,U,A1; A0+G landed after wait.
  ST_A0(0) ST_G(0) ST_U(0) ST_A1(0)
  WAITV4(); BAR(); SCHED0();

  for (int kt = 0; kt < NT1; ++kt) {
    const u16* A0 = AL[kt & 1][0];
    const u16* A1 = AL[kt & 1][1];
    const u16* G  = GL[kt & 1];
    const u16* U  = UL[kt & 1];
    const int st = (kt + 1 < NT1);
    // ---- P0: read A0 + Bg; stage A0'; MFMA accg[0-3] (16)
#pragma unroll
    for (int i = 0; i < 4; ++i) {
      af[i][0] = *(const bf16x8*)&A0[rA + i * 1024 + sw0];
      af[i][1] = *(const bf16x8*)&A0[rA + i * 1024 + sw1];
    }
#pragma unroll
    for (int n = 0; n < 2; ++n) {
      bgf[n][0] = *(const bf16x8*)&G[rB + n * 1024 + sw0];
      bgf[n][1] = *(const bf16x8*)&G[rB + n * 1024 + sw1];
    }
    if (st) ST_A0(kt + 1)
    PRIO1();
#pragma unroll
    for (int ks = 0; ks < 2; ++ks)
#pragma unroll
      for (int i = 0; i < 4; ++i)
#pragma unroll
        for (int n = 0; n < 2; ++n)
          accg[i][n] = MFMA(af[i][ks], bgf[n][ks], accg[i][n]);
    PRIO0();
    if (st) { WAITV4(); } else { WAITV2(); }
    BAR(); SCHED0();
    // ---- P1: read Bu; stage G'+U'; MFMA accu[0-3] (16)
#pragma unroll
    for (int n = 0; n < 2; ++n) {
      buf[n][0] = *(const bf16x8*)&U[rB + n * 1024 + sw0];
      buf[n][1] = *(const bf16x8*)&U[rB + n * 1024 + sw1];
    }
    if (st) { ST_G(kt + 1) ST_U(kt + 1) }
    PRIO1();
#pragma unroll
    for (int ks = 0; ks < 2; ++ks)
#pragma unroll
      for (int i = 0; i < 4; ++i)
#pragma unroll
        for (int n = 0; n < 2; ++n)
          accu[i][n] = MFMA(af[i][ks], buf[n][ks], accu[i][n]);
    PRIO0();
    if (st) { WAITV6(); } else { WAITV0(); }
    BAR(); SCHED0();
    // ---- P2: read A1; stage A1'; MFMA accg[4-7]+accu[4-7] (32)
#pragma unroll
    for (int i = 0; i < 4; ++i) {
      af[i][0] = *(const bf16x8*)&A1[rA + i * 1024 + sw0];
      af[i][1] = *(const bf16x8*)&A1[rA + i * 1024 + sw1];
    }
    if (st) ST_A1(kt + 1)
    PRIO1();
#pragma unroll
    for (int ks = 0; ks < 2; ++ks)
#pragma unroll
      for (int i = 0; i < 4; ++i)
#pragma unroll
        for (int n = 0; n < 2; ++n) {
          accg[4 + i][n] = MFMA(af[i][ks], bgf[n][ks], accg[4 + i][n]);
          accu[4 + i][n] = MFMA(af[i][ks], buf[n][ks], accu[4 + i][n]);
        }
    PRIO0();
    WAITV4();
    BAR(); SCHED0();
  }

  // epilogue: silu(g+bg)*(u+bu) -> bf16; pad cols [DFF, ACT_P) get 0.
  // Fast math: v_exp + v_rcp (1-ulp f32, invisible in bf16 output).
#pragma unroll
  for (int f = 0; f < 8; ++f) {
    const int rbase = bm * 256 + (f >> 2) * 128 + wm * 64 + (f & 3) * 16 + ck * 4;
#pragma unroll
    for (int v = 0; v < 4; ++v) {
      u16* arow = act + (size_t)(rbase + v) * ACT_P;
#pragma unroll
      for (int n = 0; n < 2; ++n) {
        const int col = bn * 128 + wn * 32 + n * 16 + fr;
        u16 ov = 0;
        if (col < DFF) {
          float gv = accg[f][n][v] + bg[col];
          float uv = accu[f][n][v] + bu[col];
          float e = __expf(-gv);
          float sv = gv * __builtin_amdgcn_rcpf(1.0f + e);
          ov = f2bf(sv * uv);
        }
        arow[col] = ov;
      }
    }
  }
#undef ST_A0
#undef ST_A1
#undef ST_G
#undef ST_U
}

// GEMM2: Yslot[slot] = selW[slot] * (act[slot]*WdT + bd)  (dense, no atomics)
// Block tile 256M x 256N, wave tile 128M x 64N. Grid 32bm x 8bn = 256 = 8*32.
// XCD mapping: bn-per-XCD (B panel 2.8 MB L2-resident) -- unchanged.
__global__ __launch_bounds__(512, 2) void gemm2_kernel(
    const u16* __restrict__ act,   // [8192][5504] bf16
    const u16* __restrict__ WdT,   // [2048][5504] bf16
    const float* __restrict__ bd,  // [2048]
    const float* __restrict__ selW,
    float* __restrict__ Yslot)     // [8192][2048] fp32 slot-major
{
  __shared__ u16 AL[2][2][8192];   // 64 KB
  __shared__ u16 BL[2][2][8192];   // 64 KB

  const int id = blockIdx.x;                  // 256 = 8 * 32
  const int wg = (id & 7) * 32 + (id >> 3);
  const int bm = wg & 31, bn = wg >> 5;

  const int tid = threadIdx.x;
  const int lane = tid & 63, wid = tid >> 6;
  const int wm = wid >> 2, wn = wid & 3;
  const int fr = lane & 15, ck = lane >> 4;
  const int sw0 = (ck ^ (fr & 7)) * 8;
  const int sw1 = sw0 ^ 32;
  const int rA = (wm * 64 + fr) * 64;
  const int rB = (wn * 32 + fr) * 64;

  const int sr = tid >> 3;
  const int sq = (tid & 7) ^ (sr & 7);
  const u16* aS0 = act + (size_t)(bm * 256 + sr) * ACT_P + sq * 8;
  const u16* aS1 = aS0 + (size_t)128 * ACT_P;
  const u16* bS0 = WdT + (size_t)(bn * 256 + sr) * ACT_P + sq * 8;
  const u16* bS1 = bS0 + (size_t)128 * ACT_P;

#define ST_A0(kt) { u16* d = &AL[(kt)&1][0][tid*8]; \
    STG(aS0 + (kt)*64, d); STG(aS0 + (kt)*64 + (size_t)64*ACT_P, d + 4096); }
#define ST_A1(kt) { u16* d = &AL[(kt)&1][1][tid*8]; \
    STG(aS1 + (kt)*64, d); STG(aS1 + (kt)*64 + (size_t)64*ACT_P, d + 4096); }
#define ST_B0(kt) { u16* d = &BL[(kt)&1][0][tid*8]; \
    STG(bS0 + (kt)*64, d); STG(bS0 + (kt)*64 + (size_t)64*ACT_P, d + 4096); }
#define ST_B1(kt) { u16* d = &BL[(kt)&1][1][tid*8]; \
    STG(bS1 + (kt)*64, d); STG(bS1 + (kt)*64 + (size_t)64*ACT_P, d + 4096); }

  f32x4 acc[8][4];
  const f32x4 z4 = {0.f, 0.f, 0.f, 0.f};
#pragma unroll
  for (int i = 0; i < 8; ++i)
#pragma unroll
    for (int n = 0; n < 4; ++n) acc[i][n] = z4;

  bf16x8 af[4][2], b0[2][2], b1[2][2];

  ST_A0(0) ST_B0(0) ST_B1(0) ST_A1(0)
  WAITV4(); BAR(); SCHED0();

  for (int kt = 0; kt < NT2; ++kt) {
    const u16* A0 = AL[kt & 1][0];
    const u16* A1 = AL[kt & 1][1];
    const u16* B0 = BL[kt & 1][0];
    const u16* B1 = BL[kt & 1][1];
    const int st = (kt + 1 < NT2);
    // ---- P0: read A0 + B0; stage A0'; MFMA acc[0-3][0-1] (16)
#pragma unroll
    for (int i = 0; i < 4; ++i) {
      af[i][0] = *(const bf16x8*)&A0[rA + i * 1024 + sw0];
      af[i][1] = *(const bf16x8*)&A0[rA + i * 1024 + sw1];
    }
#pragma unroll
    for (int n = 0; n < 2; ++n) {
      b0[n][0] = *(const bf16x8*)&B0[rB + n * 1024 + sw0];
      b0[n][1] = *(const bf16x8*)&B0[rB + n * 1024 + sw1];
    }
    if (st) ST_A0(kt + 1)
    PRIO1();
#pragma unroll
    for (int ks = 0; ks < 2; ++ks)
#pragma unroll
      for (int i = 0; i < 4; ++i)
#pragma unroll
        for (int n = 0; n < 2; ++n)
          acc[i][n] = MFMA(af[i][ks], b0[n][ks], acc[i][n]);
    PRIO0();
    if (st) { WAITV4(); } else { WAITV2(); }
    BAR(); SCHED0();
    // ---- P1: read B1; stage B0'+B1'; MFMA acc[0-3][2-3] (16)
#pragma unroll
    for (int n = 0; n < 2; ++n) {
      b1[n][0] = *(const bf16x8*)&B1[rB + n * 1024 + sw0];
      b1[n][1] = *(const bf16x8*)&B1[rB + n * 1024 + sw1];
    }
    if (st) { ST_B0(kt + 1) ST_B1(kt + 1) }
    PRIO1();
#pragma unroll
    for (int ks = 0; ks < 2; ++ks)
#pragma unroll
      for (int i = 0; i < 4; ++i)
#pragma unroll
        for (int n = 0; n < 2; ++n)
          acc[i][2 + n] = MFMA(af[i][ks], b1[n][ks], acc[i][2 + n]);
    PRIO0();
    if (st) { WAITV6(); } else { WAITV0(); }
    BAR(); SCHED0();
    // ---- P2: read A1; stage A1'; MFMA acc[4-7][0-3] (32)
#pragma unroll
    for (int i = 0; i < 4; ++i) {
      af[i][0] = *(const bf16x8*)&A1[rA + i * 1024 + sw0];
      af[i][1] = *(const bf16x8*)&A1[rA + i * 1024 + sw1];
    }
    if (st) ST_A1(kt + 1)
    PRIO1();
#pragma unroll
    for (int ks = 0; ks < 2; ++ks)
#pragma unroll
      for (int i = 0; i < 4; ++i)
#pragma unroll
        for (int n = 0; n < 2; ++n) {
          acc[4 + i][n]     = MFMA(af[i][ks], b0[n][ks], acc[4 + i][n]);
          acc[4 + i][2 + n] = MFMA(af[i][ks], b1[n][ks], acc[4 + i][2 + n]);
        }
    PRIO0();
    WAITV4();
    BAR(); SCHED0();
  }

  // epilogue: weighted dense store (no atomics)
#pragma unroll
  for (int f = 0; f < 8; ++f) {
    const int rbase = bm * 256 + (f >> 2) * 128 + wm * 64 + (f & 3) * 16 + ck * 4;
#pragma unroll
    for (int v = 0; v < 4; ++v) {
      const int srow = rbase + v;
      const float w = selW[srow];
      float* yrow = Yslot + (size_t)srow * HDIM;
#pragma unroll
      for (int n = 0; n < 4; ++n) {
        const int col = bn * 256 + (n >> 1) * 128 + wn * 32 + (n & 1) * 16 + fr;
        yrow[col] = w * (acc[f][n][v] + bd[col]);
      }
    }
  }
#undef ST_A0
#undef ST_A1
#undef ST_B0
#undef ST_B1
}

// ---------------- scatter: y[tok] = sum over experts of Yslot[inv[e][tok]]
__global__ __launch_bounds__(256) void scatter_kernel(const float* __restrict__ Yslot,
    const int* __restrict__ inv, float* __restrict__ y)
{
  const int t = blockIdx.x;
  const int c = threadIdx.x * 8;
  float4 a0 = {0.f,0.f,0.f,0.f}, a1 = {0.f,0.f,0.f,0.f};
#pragma unroll
  for (int e = 0; e < 8; ++e) {
    const int s = inv[e * N_TOK + t];
    if (s >= 0) {
      const float4* p = (const float4*)(Yslot + (size_t)s * HDIM + c);
      float4 v0 = p[0], v1 = p[1];
      a0.x += v0.x; a0.y += v0.y; a0.z += v0.z; a0.w += v0.w;
      a1.x += v1.x; a1.y += v1.y; a1.z += v1.z; a1.w += v1.w;
    }
  }
  float4* yp = (float4*)(y + (size_t)t * HDIM + c);
  yp[0] = a0; yp[1] = a1;
}

extern "C" void kernel_launch(void* const* d_in, const int* in_sizes, int n_in,
                              void* d_out, int out_size, void* d_ws, size_t ws_size,
                              hipStream_t stream) {
  const float* x      = (const float*)d_in[0];
  const float* rw     = (const float*)d_in[1];
  const float* rb     = (const float*)d_in[2];
  const float* w_gate = (const float*)d_in[3];
  const float* b_gate = (const float*)d_in[4];
  const float* w_up   = (const float*)d_in[5];
  const float* b_up   = (const float*)d_in[6];
  const float* w_down = (const float*)d_in[7];
  const float* b_down = (const float*)d_in[8];
  float* y = (float*)d_out;

  // Workspace layout (max end 180,158,464 B; aliasing by lifetime):
  //  [0,32K)        selTok          (live: select..gather)
  //  [32K,64K)      selW            (live through gemm2)
  //  [64K,320K)     inv             (live through scatter)
  //  [320K,90.5M)   act [8192][5504] bf16 (gemm1 -> gemm2)
  //  [90.5M,124.06M) Xsel [8192][2048] bf16 (gather->gemm1); WdT aliases
  //                 here (transposed AFTER gemm1, read by gemm2)
  //  [113.05M,180.2M) Yslot [8192][2048] f32 (gemm2->scatter); overlays
  //                 SmT/WgT/WuT which are dead after gemm1
  //  [124.06M,124.3M) SmT (router->select)
  //  [124.3M,146.9M)  WgT ; [146.9M,169.4M) WuT (transpose->gemm1)
  uint8_t* ws = (uint8_t*)d_ws;
  uint32_t* selTok = (uint32_t*)(ws + 0);
  float*    selW   = (float*)(ws + 32768);
  int*      inv    = (int*)(ws + 65536);
  u16*      act    = (u16*)(ws + 327680);
  u16*      Xsel   = (u16*)(ws + 90505216ull);
  u16*      WdT    = (u16*)(ws + 90505216ull);
  float*    Yslot  = (float*)(ws + 113049600ull);
  float*    SmT    = (float*)(ws + 124059648ull);
  u16*      WgT    = (u16*)(ws + 124321792ull);
  u16*      WuT    = (u16*)(ws + 146866176ull);

  hipMemsetAsync(inv, 0xFF, NEXP * N_TOK * sizeof(int), stream);
  transpose_convert<<<dim3(172, 64), dim3(32, 8), 0, stream>>>(w_gate, 2048, DFF, WgT, 2048);
  transpose_convert<<<dim3(172, 64), dim3(32, 8), 0, stream>>>(w_up,   2048, DFF, WuT, 2048);
  router_kernel<<<N_TOK / 4, 256, 0, stream>>>(x, rw, rb, SmT);
  select_topk<<<NEXP, 1024, 0, stream>>>(SmT, selTok, selW);
  build_inv<<<N_TOK / 256, 256, 0, stream>>>(selTok, inv);
  gather_kernel<<<N_TOK, 256, 0, stream>>>(x, selTok, Xsel);
  gemm1_kernel<<<43 * 32, 512, 0, stream>>>(Xsel, WgT, WuT, b_gate, b_up, act);
  transpose_convert<<<dim3(64, 172), dim3(32, 8), 0, stream>>>(w_down, DFF, 2048, WdT, ACT_P);
  gemm2_kernel<<<8 * 32, 512, 0, stream>>>(act, WdT, b_down, selW, Yslot);
  scatter_kernel<<<N_TOK, 256, 0, stream>>>(Yslot, inv, y);
}